// Round 2
// baseline (1092.043 us; speedup 1.0000x reference)
//
#include <hip/hip_runtime.h>
#include <hip/hip_bf16.h>

#define N_NODES 50000
#define N_EDGES 800000
#define D_NODE  128
#define D_EDGE  64
#define D_GLOB  64
#define D_IN    384
#define D_OUT   128

// padded K pitch for the LDS A-tile (bf16 elements): 392*2B = 784 B = 196 words;
// 196 % 32 = 4 -> at most 2-way bank aliasing on ds_read_b128 (free on gfx950).
#define APITCH  392

typedef __attribute__((ext_vector_type(4))) float  floatx4;
typedef __attribute__((ext_vector_type(8))) short  shortx8;

// load 8 consecutive fp32 (32 B, caller guarantees alignment) -> 8 bf16 (RNE)
__device__ __forceinline__ shortx8 cvt8_bf16(const float* __restrict__ p) {
    floatx4 a = *(const floatx4*)p;
    floatx4 b = *(const floatx4*)(p + 4);
    shortx8 r;
    union { __hip_bfloat16 h; short s; } u;
    #pragma unroll
    for (int j = 0; j < 4; ++j) {
        u.h = __float2bfloat16(a[j]); r[j]     = u.s;
        u.h = __float2bfloat16(b[j]); r[j + 4] = u.s;
    }
    return r;
}

__global__ __launch_bounds__(256, 2)
void edge_mlp_kernel(const float* __restrict__ node,
                     const float* __restrict__ edgef,
                     const float* __restrict__ globf,
                     const int* __restrict__ eidx,      // [2, E] int32 (or int64, sniffed)
                     const int* __restrict__ batch,     // [N]
                     const float* __restrict__ W,       // [128, 384] fp32
                     float* __restrict__ out)           // [E, 128] fp32
{
    __shared__ short A_lds[64 * APITCH];   // 50176 B, bf16 bit patterns

    const int tid = threadIdx.x;
    const int e0  = blockIdx.x * 64;

    // int64-vs-int32 layout sniff: little-endian int64 values < 2^31 have all
    // high words == 0. Prob. of false positive with real int32 data ~ (1/5e4)^8.
    // Deterministic (pristine inputs) -> graph-capture safe.
    const int is64 = ((eidx[1] | eidx[3] | eidx[5] | eidx[7] |
                       eidx[9] | eidx[11] | eidx[13] | eidx[15]) == 0) ? 1 : 0;

    // ---------- stage gathered+concat A-tile: 64 edges x 384 bf16 ----------
    // 64*48 = 3072 groups of 8 elements; 256 threads -> 12 groups each.
    #pragma unroll
    for (int i = 0; i < 12; ++i) {
        int g       = tid + i * 256;
        int e_local = g / 48;                 // 48 groups per edge row
        int off     = (g - e_local * 48) * 8; // element offset in [0,384)
        int e       = e0 + e_local;
        const float* srcp;
        if (off < 128) {
            int s = eidx[(size_t)e << is64];
            srcp = node + (size_t)s * D_NODE + off;
        } else if (off < 256) {
            int d = eidx[(size_t)(N_EDGES + e) << is64];
            srcp = node + (size_t)d * D_NODE + (off - 128);
        } else if (off < 320) {
            srcp = edgef + (size_t)e * D_EDGE + (off - 256);
        } else {
            int s = eidx[(size_t)e << is64];
            int b = batch[(size_t)s << is64];
            srcp = globf + (size_t)b * D_GLOB + (off - 320);
        }
        *(shortx8*)(&A_lds[e_local * APITCH + off]) = cvt8_bf16(srcp);
    }

    // ---------- per-wave B fragments (registers for whole kernel) ----------
    const int wave = tid >> 6;
    const int lane = tid & 63;
    const int nlo  = lane & 15;      // N index within 16-tile / C col
    const int quad = lane >> 4;      // K sub-chunk selector / C row quad

    // wave w owns output channels [w*32, w*32+32)
    shortx8 bfrag[12][2];
    #pragma unroll
    for (int kc = 0; kc < 12; ++kc) {
        #pragma unroll
        for (int nt = 0; nt < 2; ++nt) {
            int n = wave * 32 + nt * 16 + nlo;
            // B[k][n] = W[n][k]: 8 consecutive fp32 along W's row
            bfrag[kc][nt] = cvt8_bf16(W + (size_t)n * D_IN + kc * 32 + quad * 8);
        }
    }

    floatx4 acc[4][2];
    #pragma unroll
    for (int mt = 0; mt < 4; ++mt)
        #pragma unroll
        for (int nt = 0; nt < 2; ++nt)
            acc[mt][nt] = (floatx4){0.f, 0.f, 0.f, 0.f};

    __syncthreads();

    // ---------- K loop: 12 chunks x 4 m-tiles x 2 n-tiles ------------------
    #pragma unroll
    for (int kc = 0; kc < 12; ++kc) {
        #pragma unroll
        for (int mt = 0; mt < 4; ++mt) {
            // A frag: A[m = lane&15][k = kc*32 + quad*8 + j] -> ds_read_b128
            shortx8 afrag = *(const shortx8*)(
                &A_lds[(mt * 16 + nlo) * APITCH + kc * 32 + quad * 8]);
            #pragma unroll
            for (int nt = 0; nt < 2; ++nt) {
                acc[mt][nt] = __builtin_amdgcn_mfma_f32_16x16x32_bf16(
                    afrag, bfrag[kc][nt], acc[mt][nt], 0, 0, 0);
            }
        }
    }

    // ---------- epilogue: shifted softplus, fp32 store ---------------------
    // C/D layout: col = lane&15 (n), row = quad*4 + reg (m)
    #pragma unroll
    for (int mt = 0; mt < 4; ++mt) {
        #pragma unroll
        for (int nt = 0; nt < 2; ++nt) {
            int n = wave * 32 + nt * 16 + nlo;
            #pragma unroll
            for (int r = 0; r < 4; ++r) {
                int e = e0 + mt * 16 + quad * 4 + r;
                float h  = acc[mt][nt][r];
                // stable softplus: max(h,0) + log(1 + exp(-|h|)), then - ln 2
                float t  = __expf(-fabsf(h));
                float sp = fmaxf(h, 0.0f) + __logf(1.0f + t);
                out[(size_t)e * D_OUT + n] = sp - 0.69314718055994531f;
            }
        }
    }
}

extern "C" void kernel_launch(void* const* d_in, const int* in_sizes, int n_in,
                              void* d_out, int out_size, void* d_ws, size_t ws_size,
                              hipStream_t stream) {
    const float* node  = (const float*)d_in[0];
    const float* edgef = (const float*)d_in[1];
    const float* globf = (const float*)d_in[2];
    const int*   eidx  = (const int*)d_in[3];
    const int*   batch = (const int*)d_in[4];
    const float* W     = (const float*)d_in[5];
    float*       out   = (float*)d_out;

    dim3 grid(N_EDGES / 64);   // 800000 / 64 = 12500 exactly
    dim3 block(256);
    edge_mlp_kernel<<<grid, block, 0, stream>>>(node, edgef, globf, eidx, batch, W, out);
}